// Round 10
// baseline (365938.721 us; speedup 1.0000x reference)
//
#include <hip/hip_runtime.h>

// MoE GLU MLP: E=8, D=1024, H=1024, K=2, N=2048 tokens, 4096 pairs.
// R17: fuse prep + gemm1 into ONE mega-kernel with fine-grained release/acquire
// flags so conversion work overlaps gemm1's latency stalls (m114 mechanism at
// dispatch scale). Block-id order (deps point strictly to lower ids => no deadlock
// with in-order dispatch): [bucket 8 | xcvt 256 | W1cvt 2048 e-major |
// per-e: W2cvt 128 + gemm1 192 | outzero 512].
//   producer release: __syncthreads (drains vmcnt) + __threadfence (agent fence,
//     L2 writeback) + atomicAdd(flag)
//   consumer acquire: tid0 bounded-spin on device-scope atomic load + __threadfence
//     (invalidates stale L2 lines; cross-XCD safety per G16) + __syncthreads.
// Flags live in ws (harness zero-fills ws each iteration - the 256MiB fill in the
// counters); spin is BOUNDED so a wrong assumption fails verification, not hangs.
// gemm2 unchanged from R16 (needs all of act; kernel boundary is its barrier).

typedef __bf16 bf16x8 __attribute__((ext_vector_type(8)));
typedef __bf16 bf16x4 __attribute__((ext_vector_type(4)));
typedef float  f32x4  __attribute__((ext_vector_type(4)));

#define NPAIR 4096
#define NTOK  2048
#define DDIM  1024
#define HDIM  1024
#define NEXP  8

// workspace layout (bytes)
#define ORDER_I   64                      // int index of order[] in wsi
#define FLAGS_I   5120                    // int index of flags (byte 20480)
#define FB        0                       // F[FB+e]  : bucket(e) done (target 1)
#define FX        8                       // F[FX]    : all xcvt done (target 256)
#define FW1       9                       // F[FW1+e] : W1cvt(e) done (target 256)
#define XB_OFF    (24576)                 // bf16 x        [2048][1024]   4 MB
#define W1T_OFF   (XB_OFF + 4194304)      // bf16 W1^T  [8][2048][1024]  32 MB
#define W2T_OFF   (W1T_OFF + 33554432)    // bf16 W2^T  [8][1024][1024]  16 MB
#define ACT_OFF   (W2T_OFF + 16777216)    // bf16 act      [5120][1024] 10.5 MB

#define GLOAD_LDS16(g, l) \
    __builtin_amdgcn_global_load_lds( \
        (const __attribute__((address_space(1))) void*)(g), \
        (__attribute__((address_space(3))) void*)(l), 16, 0, 0)

__device__ __forceinline__ void release_inc(int* f) {
    __threadfence();                      // agent fence: prior stores -> coherent point
    atomicAdd(f, 1);
}
__device__ __forceinline__ void acquire_wait(int* f, int target) {
    for (int i = 0; i < 200000; ++i) {    // bounded: ~25ms max; healthy wait << 100us
        if (__hip_atomic_load(f, __ATOMIC_RELAXED, __HIP_MEMORY_SCOPE_AGENT) >= target)
            return;
        __builtin_amdgcn_s_sleep(8);
    }
}

// 64k x 128c transpose-convert: global_load_lds stage -> one barrier ->
// 8x ds_read_b128 per thread -> reg 8x4 transpose -> bf16x8 stores.
__device__ __forceinline__ void tcvt2(const float* __restrict__ s,
                                      __bf16* __restrict__ d,
                                      int R, int C, int k0, int c0,
                                      float* tt, int tid) {
#pragma unroll
    for (int j = 0; j < 8; j++) {
        int c = j * 256 + tid;
        int row = c >> 5, col = (c & 31) * 4;
        GLOAD_LDS16(s + (size_t)(k0 + row) * C + c0 + col, (char*)tt + c * 16);
    }
    __syncthreads();                       // drains vmcnt(0) + barrier
    const int a = tid >> 5, b = tid & 31;
    f32x4 v[8];
#pragma unroll
    for (int jj = 0; jj < 8; jj++)
        v[jj] = *(const f32x4*)(tt + (8 * a + jj) * 128 + 4 * b);
#pragma unroll
    for (int ii = 0; ii < 4; ii++) {
        bf16x8 o;
#pragma unroll
        for (int jj = 0; jj < 8; jj++) o[jj] = (__bf16)v[jj][ii];
        *(bf16x8*)(d + (size_t)(c0 + 4 * b + ii) * R + k0 + 8 * a) = o;
    }
}

// ---------------- mega: bucket | xcvt | W1cvt | per-e {W2cvt, gemm1} | outzero ----------------
__global__ __launch_bounds__(256) void mega_kernel(const float* __restrict__ x,
                                                   const float* __restrict__ W1,
                                                   const float* __restrict__ W2,
                                                   const int* __restrict__ idx,
                                                   int* __restrict__ wsi,
                                                   __bf16* __restrict__ xb,
                                                   __bf16* __restrict__ w1t,
                                                   __bf16* __restrict__ w2t,
                                                   __bf16* __restrict__ act,
                                                   float* __restrict__ out) {
    __shared__ __align__(16) char smem[49152];   // GEMM: 2x(As 8K|Bs 16K); cvt: 32K fp32
    const int b = blockIdx.x;
    const int tid = threadIdx.x;
    int* F = wsi + FLAGS_I;

    if (b < 8) {
        // ---- bucket(e = b) ----
        __shared__ int cnt[NEXP];
        __shared__ int sbase, scur;
        const int e = b;
        if (tid < NEXP) cnt[tid] = 0;
        if (tid == 0) scur = 0;
        __syncthreads();
        for (int i = tid; i < NPAIR; i += 256) atomicAdd(&cnt[idx[i] & 7], 1);
        __syncthreads();
        if (tid == 0) {
            int off = 0;
            for (int e2 = 0; e2 < NEXP; e2++) {
                if (e2 == e) { wsi[e] = cnt[e]; wsi[8 + e] = off; sbase = off; }
                off += (cnt[e2] + 127) & ~127;
            }
        }
        __syncthreads();
        for (int i = tid; i < NPAIR; i += 256) {
            if ((idx[i] & 7) == e) {
                int s = atomicAdd(&scur, 1);
                wsi[ORDER_I + sbase + s] = i;
            }
        }
        __syncthreads();
        if (tid == 0) release_inc(&F[FB + e]);
        return;
    }
    if (b < 264) {
        // ---- xcvt (256 blocks x 8192 elems) ----
        size_t base = (size_t)(b - 8) * 8192 + tid * 8;
#pragma unroll
        for (int j = 0; j < 4; j++) {
            const float* sp = x + base + j * 2048;
            f32x4 v0 = *(const f32x4*)sp;
            f32x4 v1 = *(const f32x4*)(sp + 4);
            bf16x8 o;
            o[0] = (__bf16)v0[0]; o[1] = (__bf16)v0[1]; o[2] = (__bf16)v0[2]; o[3] = (__bf16)v0[3];
            o[4] = (__bf16)v1[0]; o[5] = (__bf16)v1[1]; o[6] = (__bf16)v1[2]; o[7] = (__bf16)v1[3];
            *(bf16x8*)(xb + base + j * 2048) = o;
        }
        __syncthreads();
        if (tid == 0) release_inc(&F[FX]);
        return;
    }
    if (b < 2312) {
        // ---- W1cvt, e-major (256 tiles/e) ----
        int i = b - 264;
        int e = i >> 8, t2 = i & 255;
        int k0 = (t2 & 15) * 64, c0 = (t2 >> 4) * 128;
        tcvt2(W1 + (size_t)e * DDIM * 2 * HDIM, w1t + (size_t)e * 2 * HDIM * DDIM,
              DDIM, 2 * HDIM, k0, c0, (float*)smem, tid);
        __syncthreads();
        if (tid == 0) release_inc(&F[FW1 + e]);
        return;
    }
    if (b >= 4872) {
        // ---- outzero (512 blocks zero 8 MB of out) ----
        int zb = b - 4872;
        float4 z4 = {0.f, 0.f, 0.f, 0.f};
        int b4 = zb * 4096;
#pragma unroll
        for (int j = 0; j < 4; j++)
            *(float4*)(out + b4 + j * 1024 + tid * 4) = z4;
        return;
    }

    // ---- per-e group: W2cvt (r<128) then gemm1 (r>=128) ----
    int i = b - 2312;
    const int e = i / 320;
    int r = i % 320;
    if (r < 128) {
        int k0 = (r & 15) * 64, c0 = (r >> 4) * 128;
        tcvt2(W2 + (size_t)e * HDIM * DDIM, w2t + (size_t)e * DDIM * HDIM,
              HDIM, DDIM, k0, c0, (float*)smem, tid);
        return;
    }
    r -= 128;                                // 0..191: n0t = r/12, mt = r%12
    const int n0 = (r / 12) * 64;
    const int m0 = (r % 12) * 64;

    // ---- acquire deps: bucket(e), all xcvt, W1cvt(e) ----
    if (tid == 0) {
        acquire_wait(&F[FB + e], 1);
        acquire_wait(&F[FX], 256);
        acquire_wait(&F[FW1 + e], 256);
        __threadfence();                     // acquire: invalidate stale cache lines
    }
    __syncthreads();

    const int cnt = wsi[e];
    if (m0 >= cnt) return;
    const int base = wsi[8 + e];
    const int* order = wsi + ORDER_I;
    const __bf16* w1e = w1t + (size_t)e * 2048 * 1024;

    const int lane = tid & 63, w = tid >> 6;
    const int lm = lane & 15, q = lane >> 4;
    const int wm = w & 1, wn = w >> 1;
    const int x7 = lm & 7;
    const int sw0 = (q ^ x7) * 16;
    const int sw1 = ((4 + q) ^ x7) * 16;

    const __bf16* ga[2];
    const __bf16* gb[4];
#pragma unroll
    for (int j = 0; j < 2; j++) {
        int c = j * 256 + tid;
        int rr2 = c >> 3;
        int ks = ((c & 7) ^ (rr2 & 7)) * 8;
        int m = m0 + rr2; if (m >= cnt) m = cnt - 1;
        int tok = order[base + m] >> 1;
        ga[j] = xb + (size_t)tok * DDIM + ks;
    }
#pragma unroll
    for (int j = 0; j < 4; j++) {
        int c = j * 256 + tid;
        int rr2 = c >> 3;
        int ks = ((c & 7) ^ (rr2 & 7)) * 8;
        int half = rr2 >> 6, rr = rr2 & 63;
        int rb = (rr < 32) ? (n0 + half * 32 + rr)
                           : (HDIM + n0 + half * 32 + (rr - 32));
        gb[j] = w1e + (size_t)rb * DDIM + ks;
    }

    f32x4 acc[2][4];
#pragma unroll
    for (int mt = 0; mt < 2; mt++)
#pragma unroll
        for (int nt = 0; nt < 4; nt++) acc[mt][nt] = (f32x4){0.f, 0.f, 0.f, 0.f};

    // ---- prologue: issue tile 0 into buf0 (no drain) ----
#pragma unroll
    for (int j = 0; j < 2; j++) {
        GLOAD_LDS16(ga[j], smem + (j * 256 + tid) * 16);
        ga[j] += 64;
    }
#pragma unroll
    for (int j = 0; j < 4; j++) {
        GLOAD_LDS16(gb[j], smem + 8192 + (j * 256 + tid) * 16);
        gb[j] += 64;
    }

    // ---- 2-phase main loop, counted vmcnt ----
    for (int t = 0; t < 16; ++t) {
        char* cbase = smem + (t & 1) * 24576;
        if (t < 15) {
            char* nbase = smem + ((t + 1) & 1) * 24576;
#pragma unroll
            for (int j = 0; j < 2; j++) {
                GLOAD_LDS16(ga[j], nbase + (j * 256 + tid) * 16);
                ga[j] += 64;
            }
#pragma unroll
            for (int j = 0; j < 4; j++) {
                GLOAD_LDS16(gb[j], nbase + 8192 + (j * 256 + tid) * 16);
                gb[j] += 64;
            }
            asm volatile("s_waitcnt vmcnt(6)" ::: "memory");   // tile t landed
        } else {
            asm volatile("s_waitcnt vmcnt(0)" ::: "memory");
        }
        __builtin_amdgcn_s_barrier();
        __builtin_amdgcn_sched_barrier(0);
        __bf16 (*As)[64] = (__bf16 (*)[64])cbase;
        __bf16 (*Bs)[64] = (__bf16 (*)[64])(cbase + 8192);
#pragma unroll
        for (int kh = 0; kh < 2; kh++) {
            const int sw = kh ? sw1 : sw0;
            bf16x8 af[2];
#pragma unroll
            for (int mt = 0; mt < 2; mt++)
                af[mt] = *(const bf16x8*)((const char*)&As[wm * 32 + mt * 16 + lm][0] + sw);
            __builtin_amdgcn_s_setprio(1);
#pragma unroll
            for (int nt = 0; nt < 4; nt++) {
                bf16x8 bfr = *(const bf16x8*)((const char*)&Bs[wn * 64 + nt * 16 + lm][0] + sw);
#pragma unroll
                for (int mt = 0; mt < 2; mt++)
                    acc[mt][nt] = __builtin_amdgcn_mfma_f32_16x16x32_bf16(af[mt], bfr, acc[mt][nt], 0, 0, 0);
            }
            __builtin_amdgcn_s_setprio(0);
        }
        __builtin_amdgcn_sched_barrier(0);
        __builtin_amdgcn_s_barrier();
    }

#pragma unroll
    for (int mt = 0; mt < 2; mt++) {
        int mbase = m0 + wm * 32 + mt * 16 + q * 4;
#pragma unroll
        for (int ntp = 0; ntp < 2; ntp++) {
            int col = n0 + wn * 32 + ntp * 16 + lm;
#pragma unroll
            for (int rr = 0; rr < 4; rr++) {
                int m = mbase + rr;
                if (m < cnt) {
                    float h = acc[mt][ntp][rr];
                    float g = acc[mt][ntp + 2][rr];
                    float a = h * (g / (1.f + __expf(-g)));
                    act[(size_t)(base + m) * HDIM + col] = (__bf16)a;
                }
            }
        }
    }
}

// ---------------- gemm2: 64m x 64n, counted vmcnt, fused atomic combine (R16 exact) ----------------
__global__ __launch_bounds__(256) void gemm2_kernel(const __bf16* __restrict__ act,
                                                    const __bf16* __restrict__ w2t,
                                                    const int* __restrict__ wsi,
                                                    const float* __restrict__ p,
                                                    float* __restrict__ out) {
    const int e = blockIdx.z;
    const int cnt = wsi[e];
    const int m0 = blockIdx.y * 64;
    if (m0 >= cnt) return;
    const int base = wsi[8 + e];
    const int n0 = blockIdx.x * 64;
    const int* order = wsi + ORDER_I;
    const __bf16* w2e = w2t + (size_t)e * 1024 * 1024;

    __shared__ __align__(16) char smem[32768];   // 2 x (As 8K | Bs 8K)

    const int tid = threadIdx.x;
    const int lane = tid & 63, w = tid >> 6;
    const int lm = lane & 15, q = lane >> 4;
    const int wm = w & 1, wn = w >> 1;
    const int x7 = lm & 7;
    const int sw0 = (q ^ x7) * 16;
    const int sw1 = ((4 + q) ^ x7) * 16;

    const __bf16* ga[2];
    const __bf16* gb[2];
#pragma unroll
    for (int j = 0; j < 2; j++) {
        int c = j * 256 + tid;
        int r = c >> 3;
        int ks = ((c & 7) ^ (r & 7)) * 8;
        ga[j] = act + (size_t)(base + m0 + r) * HDIM + ks;   // pad rows masked at epilogue
        gb[j] = w2e + (size_t)(n0 + r) * HDIM + ks;
    }

    f32x4 acc[2][2];
#pragma unroll
    for (int mt = 0; mt < 2; mt++)
#pragma unroll
        for (int nt = 0; nt < 2; nt++) acc[mt][nt] = (f32x4){0.f, 0.f, 0.f, 0.f};

#pragma unroll
    for (int j = 0; j < 2; j++) {
        GLOAD_LDS16(ga[j], smem + (j * 256 + tid) * 16);
        GLOAD_LDS16(gb[j], smem + 8192 + (j * 256 + tid) * 16);
        ga[j] += 64; gb[j] += 64;
    }

    for (int t = 0; t < 16; ++t) {
        char* cbase = smem + (t & 1) * 16384;
        if (t < 15) {
            char* nbase = smem + ((t + 1) & 1) * 16384;
#pragma unroll
            for (int j = 0; j < 2; j++) {
                GLOAD_LDS16(ga[j], nbase + (j * 256 + tid) * 16);
                GLOAD_LDS16(gb[j], nbase + 8192 + (j * 256 + tid) * 16);
                ga[j] += 64; gb[j] += 64;
            }
            asm volatile("s_waitcnt vmcnt(4)" ::: "memory");   // tile t landed
        } else {
            asm volatile("s_waitcnt vmcnt(0)" ::: "memory");
        }
        __builtin_amdgcn_s_barrier();
        __builtin_amdgcn_sched_barrier(0);
        __bf16 (*As)[64] = (__bf16 (*)[64])cbase;
        __bf16 (*Bs)[64] = (__bf16 (*)[64])(cbase + 8192);
#pragma unroll
        for (int kh = 0; kh < 2; kh++) {
            const int sw = kh ? sw1 : sw0;
            bf16x8 af[2];
#pragma unroll
            for (int mt = 0; mt < 2; mt++)
                af[mt] = *(const bf16x8*)((const char*)&As[wm * 32 + mt * 16 + lm][0] + sw);
            __builtin_amdgcn_s_setprio(1);
#pragma unroll
            for (int nt = 0; nt < 2; nt++) {
                bf16x8 bfr = *(const bf16x8*)((const char*)&Bs[wn * 32 + nt * 16 + lm][0] + sw);
#pragma unroll
                for (int mt = 0; mt < 2; mt++)
                    acc[mt][nt] = __builtin_amdgcn_mfma_f32_16x16x32_bf16(af[mt], bfr, acc[mt][nt], 0, 0, 0);
            }
            __builtin_amdgcn_s_setprio(0);
        }
        __builtin_amdgcn_sched_barrier(0);
        __builtin_amdgcn_s_barrier();
    }

    int pi[2][4];
    float pw[2][4];
#pragma unroll
    for (int mt = 0; mt < 2; mt++)
#pragma unroll
        for (int r = 0; r < 4; r++) {
            int gm = m0 + wm * 32 + mt * 16 + q * 4 + r;
            if (gm < cnt) {
                int pr = order[base + gm];
                pi[mt][r] = pr;
                pw[mt][r] = p[pr];
            } else pi[mt][r] = -1;
        }
#pragma unroll
    for (int mt = 0; mt < 2; mt++)
#pragma unroll
        for (int nt = 0; nt < 2; nt++) {
            int col = n0 + wn * 32 + nt * 16 + lm;
#pragma unroll
            for (int r = 0; r < 4; r++) {
                if (pi[mt][r] >= 0) {
                    int tok = pi[mt][r] >> 1;
                    atomicAdd(out + (size_t)tok * DDIM + col, pw[mt][r] * acc[mt][nt][r]);
                }
            }
        }
}

extern "C" void kernel_launch(void* const* d_in, const int* in_sizes, int n_in,
                              void* d_out, int out_size, void* d_ws, size_t ws_size,
                              hipStream_t stream) {
    (void)in_sizes; (void)n_in; (void)out_size; (void)ws_size;
    const float* x   = (const float*)d_in[0];
    const float* p   = (const float*)d_in[1];
    const int* eidx  = (const int*)d_in[2];
    const float* W1  = (const float*)d_in[3];
    const float* W2  = (const float*)d_in[4];
    float* out = (float*)d_out;

    char* ws = (char*)d_ws;
    int* wsi     = (int*)ws;
    __bf16* xb   = (__bf16*)(ws + XB_OFF);
    __bf16* w1t  = (__bf16*)(ws + W1T_OFF);
    __bf16* w2t  = (__bf16*)(ws + W2T_OFF);
    __bf16* act  = (__bf16*)(ws + ACT_OFF);

    // 8 bucket + 256 xcvt + 2048 W1cvt + 8*(128 W2cvt + 192 gemm1) + 512 outzero = 5384
    mega_kernel<<<5384, 256, 0, stream>>>(x, W1, W2, eidx, wsi, xb, w1t, w2t, act, out);
    gemm2_kernel<<<dim3(16, 64, NEXP), 256, 0, stream>>>(act, w2t, wsi, p, out);
}

// Round 11
// 88346.368 us; speedup vs baseline: 4.1421x; 4.1421x over previous
//
#include <hip/hip_runtime.h>

// MoE GLU MLP: E=8, D=1024, H=1024, K=2, N=2048 tokens, 4096 pairs.
// R18 = R17 with the flag-placement bug fixed: flags moved from int index 5120
// (INSIDE the order[] span [64,5176) - bucket writes clobbered them, causing
// full-bound spins = 366ms) to int index 6000 (order ends <5176, xb starts 6144).
// Mechanism validated by R17: correctness passed (fences sound), occupancy 36%
// (co-residency works). Spin quantum shortened (s_sleep(2), 100K bound).
// Structure: ONE mega-kernel [bucket 8 | xcvt 256 | W1cvt 2048 e-major |
// per-e: W2cvt 128 + gemm1 192 | outzero 512] with release/acquire flags;
// gemm2 unchanged (R16 exact).

typedef __bf16 bf16x8 __attribute__((ext_vector_type(8)));
typedef __bf16 bf16x4 __attribute__((ext_vector_type(4)));
typedef float  f32x4  __attribute__((ext_vector_type(4)));

#define NPAIR 4096
#define NTOK  2048
#define DDIM  1024
#define HDIM  1024
#define NEXP  8

// workspace layout (bytes)
#define ORDER_I   64                      // int index of order[]; max extent < 5176
#define FLAGS_I   6000                    // int index of flags (order ends <5176; xb at 6144)
#define FB        0                       // F[FB+e]  : bucket(e) done (target 1)
#define FX        8                       // F[FX]    : all xcvt done (target 256)
#define FW1       9                       // F[FW1+e] : W1cvt(e) done (target 256)
#define XB_OFF    (24576)                 // bf16 x        [2048][1024]   4 MB
#define W1T_OFF   (XB_OFF + 4194304)      // bf16 W1^T  [8][2048][1024]  32 MB
#define W2T_OFF   (W1T_OFF + 33554432)    // bf16 W2^T  [8][1024][1024]  16 MB
#define ACT_OFF   (W2T_OFF + 16777216)    // bf16 act      [5120][1024] 10.5 MB

#define GLOAD_LDS16(g, l) \
    __builtin_amdgcn_global_load_lds( \
        (const __attribute__((address_space(1))) void*)(g), \
        (__attribute__((address_space(3))) void*)(l), 16, 0, 0)

__device__ __forceinline__ void release_inc(int* f) {
    __threadfence();                      // agent fence: L2 writeback of prior stores
    atomicAdd(f, 1);
}
__device__ __forceinline__ void acquire_wait(int* f, int target) {
    for (int i = 0; i < 100000; ++i) {    // bounded; healthy wait << 100us
        if (__hip_atomic_load(f, __ATOMIC_RELAXED, __HIP_MEMORY_SCOPE_AGENT) >= target)
            return;
        __builtin_amdgcn_s_sleep(2);
    }
}

// 64k x 128c transpose-convert: global_load_lds stage -> one barrier ->
// 8x ds_read_b128 per thread -> reg 8x4 transpose -> bf16x8 stores.
__device__ __forceinline__ void tcvt2(const float* __restrict__ s,
                                      __bf16* __restrict__ d,
                                      int R, int C, int k0, int c0,
                                      float* tt, int tid) {
#pragma unroll
    for (int j = 0; j < 8; j++) {
        int c = j * 256 + tid;
        int row = c >> 5, col = (c & 31) * 4;
        GLOAD_LDS16(s + (size_t)(k0 + row) * C + c0 + col, (char*)tt + c * 16);
    }
    __syncthreads();                       // drains vmcnt(0) + barrier
    const int a = tid >> 5, b = tid & 31;
    f32x4 v[8];
#pragma unroll
    for (int jj = 0; jj < 8; jj++)
        v[jj] = *(const f32x4*)(tt + (8 * a + jj) * 128 + 4 * b);
#pragma unroll
    for (int ii = 0; ii < 4; ii++) {
        bf16x8 o;
#pragma unroll
        for (int jj = 0; jj < 8; jj++) o[jj] = (__bf16)v[jj][ii];
        *(bf16x8*)(d + (size_t)(c0 + 4 * b + ii) * R + k0 + 8 * a) = o;
    }
}

// ---------------- mega: bucket | xcvt | W1cvt | per-e {W2cvt, gemm1} | outzero ----------------
__global__ __launch_bounds__(256) void mega_kernel(const float* __restrict__ x,
                                                   const float* __restrict__ W1,
                                                   const float* __restrict__ W2,
                                                   const int* __restrict__ idx,
                                                   int* __restrict__ wsi,
                                                   __bf16* __restrict__ xb,
                                                   __bf16* __restrict__ w1t,
                                                   __bf16* __restrict__ w2t,
                                                   __bf16* __restrict__ act,
                                                   float* __restrict__ out) {
    __shared__ __align__(16) char smem[49152];   // GEMM: 2x(As 8K|Bs 16K); cvt: 32K fp32
    const int b = blockIdx.x;
    const int tid = threadIdx.x;
    int* F = wsi + FLAGS_I;

    if (b < 8) {
        // ---- bucket(e = b) ----
        __shared__ int cnt[NEXP];
        __shared__ int sbase, scur;
        const int e = b;
        if (tid < NEXP) cnt[tid] = 0;
        if (tid == 0) scur = 0;
        __syncthreads();
        for (int i = tid; i < NPAIR; i += 256) atomicAdd(&cnt[idx[i] & 7], 1);
        __syncthreads();
        if (tid == 0) {
            int off = 0;
            for (int e2 = 0; e2 < NEXP; e2++) {
                if (e2 == e) { wsi[e] = cnt[e]; wsi[8 + e] = off; sbase = off; }
                off += (cnt[e2] + 127) & ~127;
            }
        }
        __syncthreads();
        for (int i = tid; i < NPAIR; i += 256) {
            if ((idx[i] & 7) == e) {
                int s = atomicAdd(&scur, 1);
                wsi[ORDER_I + sbase + s] = i;
            }
        }
        __syncthreads();
        if (tid == 0) release_inc(&F[FB + e]);
        return;
    }
    if (b < 264) {
        // ---- xcvt (256 blocks x 8192 elems) ----
        size_t base = (size_t)(b - 8) * 8192 + tid * 8;
#pragma unroll
        for (int j = 0; j < 4; j++) {
            const float* sp = x + base + j * 2048;
            f32x4 v0 = *(const f32x4*)sp;
            f32x4 v1 = *(const f32x4*)(sp + 4);
            bf16x8 o;
            o[0] = (__bf16)v0[0]; o[1] = (__bf16)v0[1]; o[2] = (__bf16)v0[2]; o[3] = (__bf16)v0[3];
            o[4] = (__bf16)v1[0]; o[5] = (__bf16)v1[1]; o[6] = (__bf16)v1[2]; o[7] = (__bf16)v1[3];
            *(bf16x8*)(xb + base + j * 2048) = o;
        }
        __syncthreads();
        if (tid == 0) release_inc(&F[FX]);
        return;
    }
    if (b < 2312) {
        // ---- W1cvt, e-major (256 tiles/e) ----
        int i = b - 264;
        int e = i >> 8, t2 = i & 255;
        int k0 = (t2 & 15) * 64, c0 = (t2 >> 4) * 128;
        tcvt2(W1 + (size_t)e * DDIM * 2 * HDIM, w1t + (size_t)e * 2 * HDIM * DDIM,
              DDIM, 2 * HDIM, k0, c0, (float*)smem, tid);
        __syncthreads();
        if (tid == 0) release_inc(&F[FW1 + e]);
        return;
    }
    if (b >= 4872) {
        // ---- outzero (512 blocks zero 8 MB of out) ----
        int zb = b - 4872;
        float4 z4 = {0.f, 0.f, 0.f, 0.f};
        int b4 = zb * 4096;
#pragma unroll
        for (int j = 0; j < 4; j++)
            *(float4*)(out + b4 + j * 1024 + tid * 4) = z4;
        return;
    }

    // ---- per-e group: W2cvt (r<128) then gemm1 (r>=128) ----
    int i = b - 2312;
    const int e = i / 320;
    int r = i % 320;
    if (r < 128) {
        int k0 = (r & 15) * 64, c0 = (r >> 4) * 128;
        tcvt2(W2 + (size_t)e * HDIM * DDIM, w2t + (size_t)e * DDIM * HDIM,
              HDIM, DDIM, k0, c0, (float*)smem, tid);
        return;
    }
    r -= 128;                                // 0..191: n0t = r/12, mt = r%12
    const int n0 = (r / 12) * 64;
    const int m0 = (r % 12) * 64;

    // ---- acquire deps: bucket(e), all xcvt, W1cvt(e) ----
    if (tid == 0) {
        acquire_wait(&F[FB + e], 1);
        acquire_wait(&F[FX], 256);
        acquire_wait(&F[FW1 + e], 256);
        __threadfence();                     // acquire: invalidate stale cache lines
    }
    __syncthreads();

    const int cnt = wsi[e];
    if (m0 >= cnt) return;
    const int base = wsi[8 + e];
    const int* order = wsi + ORDER_I;
    const __bf16* w1e = w1t + (size_t)e * 2048 * 1024;

    const int lane = tid & 63, w = tid >> 6;
    const int lm = lane & 15, q = lane >> 4;
    const int wm = w & 1, wn = w >> 1;
    const int x7 = lm & 7;
    const int sw0 = (q ^ x7) * 16;
    const int sw1 = ((4 + q) ^ x7) * 16;

    const __bf16* ga[2];
    const __bf16* gb[4];
#pragma unroll
    for (int j = 0; j < 2; j++) {
        int c = j * 256 + tid;
        int rr2 = c >> 3;
        int ks = ((c & 7) ^ (rr2 & 7)) * 8;
        int m = m0 + rr2; if (m >= cnt) m = cnt - 1;
        int tok = order[base + m] >> 1;
        ga[j] = xb + (size_t)tok * DDIM + ks;
    }
#pragma unroll
    for (int j = 0; j < 4; j++) {
        int c = j * 256 + tid;
        int rr2 = c >> 3;
        int ks = ((c & 7) ^ (rr2 & 7)) * 8;
        int half = rr2 >> 6, rr = rr2 & 63;
        int rb = (rr < 32) ? (n0 + half * 32 + rr)
                           : (HDIM + n0 + half * 32 + (rr - 32));
        gb[j] = w1e + (size_t)rb * DDIM + ks;
    }

    f32x4 acc[2][4];
#pragma unroll
    for (int mt = 0; mt < 2; mt++)
#pragma unroll
        for (int nt = 0; nt < 4; nt++) acc[mt][nt] = (f32x4){0.f, 0.f, 0.f, 0.f};

    // ---- prologue: issue tile 0 into buf0 (no drain) ----
#pragma unroll
    for (int j = 0; j < 2; j++) {
        GLOAD_LDS16(ga[j], smem + (j * 256 + tid) * 16);
        ga[j] += 64;
    }
#pragma unroll
    for (int j = 0; j < 4; j++) {
        GLOAD_LDS16(gb[j], smem + 8192 + (j * 256 + tid) * 16);
        gb[j] += 64;
    }

    // ---- 2-phase main loop, counted vmcnt ----
    for (int t = 0; t < 16; ++t) {
        char* cbase = smem + (t & 1) * 24576;
        if (t < 15) {
            char* nbase = smem + ((t + 1) & 1) * 24576;
#pragma unroll
            for (int j = 0; j < 2; j++) {
                GLOAD_LDS16(ga[j], nbase + (j * 256 + tid) * 16);
                ga[j] += 64;
            }
#pragma unroll
            for (int j = 0; j < 4; j++) {
                GLOAD_LDS16(gb[j], nbase + 8192 + (j * 256 + tid) * 16);
                gb[j] += 64;
            }
            asm volatile("s_waitcnt vmcnt(6)" ::: "memory");   // tile t landed
        } else {
            asm volatile("s_waitcnt vmcnt(0)" ::: "memory");
        }
        __builtin_amdgcn_s_barrier();
        __builtin_amdgcn_sched_barrier(0);
        __bf16 (*As)[64] = (__bf16 (*)[64])cbase;
        __bf16 (*Bs)[64] = (__bf16 (*)[64])(cbase + 8192);
#pragma unroll
        for (int kh = 0; kh < 2; kh++) {
            const int sw = kh ? sw1 : sw0;
            bf16x8 af[2];
#pragma unroll
            for (int mt = 0; mt < 2; mt++)
                af[mt] = *(const bf16x8*)((const char*)&As[wm * 32 + mt * 16 + lm][0] + sw);
            __builtin_amdgcn_s_setprio(1);
#pragma unroll
            for (int nt = 0; nt < 4; nt++) {
                bf16x8 bfr = *(const bf16x8*)((const char*)&Bs[wn * 64 + nt * 16 + lm][0] + sw);
#pragma unroll
                for (int mt = 0; mt < 2; mt++)
                    acc[mt][nt] = __builtin_amdgcn_mfma_f32_16x16x32_bf16(af[mt], bfr, acc[mt][nt], 0, 0, 0);
            }
            __builtin_amdgcn_s_setprio(0);
        }
        __builtin_amdgcn_sched_barrier(0);
        __builtin_amdgcn_s_barrier();
    }

#pragma unroll
    for (int mt = 0; mt < 2; mt++) {
        int mbase = m0 + wm * 32 + mt * 16 + q * 4;
#pragma unroll
        for (int ntp = 0; ntp < 2; ntp++) {
            int col = n0 + wn * 32 + ntp * 16 + lm;
#pragma unroll
            for (int rr = 0; rr < 4; rr++) {
                int m = mbase + rr;
                if (m < cnt) {
                    float h = acc[mt][ntp][rr];
                    float g = acc[mt][ntp + 2][rr];
                    float a = h * (g / (1.f + __expf(-g)));
                    act[(size_t)(base + m) * HDIM + col] = (__bf16)a;
                }
            }
        }
    }
}

// ---------------- gemm2: 64m x 64n, counted vmcnt, fused atomic combine (R16 exact) ----------------
__global__ __launch_bounds__(256) void gemm2_kernel(const __bf16* __restrict__ act,
                                                    const __bf16* __restrict__ w2t,
                                                    const int* __restrict__ wsi,
                                                    const float* __restrict__ p,
                                                    float* __restrict__ out) {
    const int e = blockIdx.z;
    const int cnt = wsi[e];
    const int m0 = blockIdx.y * 64;
    if (m0 >= cnt) return;
    const int base = wsi[8 + e];
    const int n0 = blockIdx.x * 64;
    const int* order = wsi + ORDER_I;
    const __bf16* w2e = w2t + (size_t)e * 1024 * 1024;

    __shared__ __align__(16) char smem[32768];   // 2 x (As 8K | Bs 8K)

    const int tid = threadIdx.x;
    const int lane = tid & 63, w = tid >> 6;
    const int lm = lane & 15, q = lane >> 4;
    const int wm = w & 1, wn = w >> 1;
    const int x7 = lm & 7;
    const int sw0 = (q ^ x7) * 16;
    const int sw1 = ((4 + q) ^ x7) * 16;

    const __bf16* ga[2];
    const __bf16* gb[2];
#pragma unroll
    for (int j = 0; j < 2; j++) {
        int c = j * 256 + tid;
        int r = c >> 3;
        int ks = ((c & 7) ^ (r & 7)) * 8;
        ga[j] = act + (size_t)(base + m0 + r) * HDIM + ks;   // pad rows masked at epilogue
        gb[j] = w2e + (size_t)(n0 + r) * HDIM + ks;
    }

    f32x4 acc[2][2];
#pragma unroll
    for (int mt = 0; mt < 2; mt++)
#pragma unroll
        for (int nt = 0; nt < 2; nt++) acc[mt][nt] = (f32x4){0.f, 0.f, 0.f, 0.f};

#pragma unroll
    for (int j = 0; j < 2; j++) {
        GLOAD_LDS16(ga[j], smem + (j * 256 + tid) * 16);
        GLOAD_LDS16(gb[j], smem + 8192 + (j * 256 + tid) * 16);
        ga[j] += 64; gb[j] += 64;
    }

    for (int t = 0; t < 16; ++t) {
        char* cbase = smem + (t & 1) * 16384;
        if (t < 15) {
            char* nbase = smem + ((t + 1) & 1) * 16384;
#pragma unroll
            for (int j = 0; j < 2; j++) {
                GLOAD_LDS16(ga[j], nbase + (j * 256 + tid) * 16);
                GLOAD_LDS16(gb[j], nbase + 8192 + (j * 256 + tid) * 16);
                ga[j] += 64; gb[j] += 64;
            }
            asm volatile("s_waitcnt vmcnt(4)" ::: "memory");   // tile t landed
        } else {
            asm volatile("s_waitcnt vmcnt(0)" ::: "memory");
        }
        __builtin_amdgcn_s_barrier();
        __builtin_amdgcn_sched_barrier(0);
        __bf16 (*As)[64] = (__bf16 (*)[64])cbase;
        __bf16 (*Bs)[64] = (__bf16 (*)[64])(cbase + 8192);
#pragma unroll
        for (int kh = 0; kh < 2; kh++) {
            const int sw = kh ? sw1 : sw0;
            bf16x8 af[2];
#pragma unroll
            for (int mt = 0; mt < 2; mt++)
                af[mt] = *(const bf16x8*)((const char*)&As[wm * 32 + mt * 16 + lm][0] + sw);
            __builtin_amdgcn_s_setprio(1);
#pragma unroll
            for (int nt = 0; nt < 2; nt++) {
                bf16x8 bfr = *(const bf16x8*)((const char*)&Bs[wn * 32 + nt * 16 + lm][0] + sw);
#pragma unroll
                for (int mt = 0; mt < 2; mt++)
                    acc[mt][nt] = __builtin_amdgcn_mfma_f32_16x16x32_bf16(af[mt], bfr, acc[mt][nt], 0, 0, 0);
            }
            __builtin_amdgcn_s_setprio(0);
        }
        __builtin_amdgcn_sched_barrier(0);
        __builtin_amdgcn_s_barrier();
    }

    int pi[2][4];
    float pw[2][4];
#pragma unroll
    for (int mt = 0; mt < 2; mt++)
#pragma unroll
        for (int r = 0; r < 4; r++) {
            int gm = m0 + wm * 32 + mt * 16 + q * 4 + r;
            if (gm < cnt) {
                int pr = order[base + gm];
                pi[mt][r] = pr;
                pw[mt][r] = p[pr];
            } else pi[mt][r] = -1;
        }
#pragma unroll
    for (int mt = 0; mt < 2; mt++)
#pragma unroll
        for (int nt = 0; nt < 2; nt++) {
            int col = n0 + wn * 32 + nt * 16 + lm;
#pragma unroll
            for (int r = 0; r < 4; r++) {
                if (pi[mt][r] >= 0) {
                    int tok = pi[mt][r] >> 1;
                    atomicAdd(out + (size_t)tok * DDIM + col, pw[mt][r] * acc[mt][nt][r]);
                }
            }
        }
}

extern "C" void kernel_launch(void* const* d_in, const int* in_sizes, int n_in,
                              void* d_out, int out_size, void* d_ws, size_t ws_size,
                              hipStream_t stream) {
    (void)in_sizes; (void)n_in; (void)out_size; (void)ws_size;
    const float* x   = (const float*)d_in[0];
    const float* p   = (const float*)d_in[1];
    const int* eidx  = (const int*)d_in[2];
    const float* W1  = (const float*)d_in[3];
    const float* W2  = (const float*)d_in[4];
    float* out = (float*)d_out;

    char* ws = (char*)d_ws;
    int* wsi     = (int*)ws;
    __bf16* xb   = (__bf16*)(ws + XB_OFF);
    __bf16* w1t  = (__bf16*)(ws + W1T_OFF);
    __bf16* w2t  = (__bf16*)(ws + W2T_OFF);
    __bf16* act  = (__bf16*)(ws + ACT_OFF);

    // 8 bucket + 256 xcvt + 2048 W1cvt + 8*(128 W2cvt + 192 gemm1) + 512 outzero = 5384
    mega_kernel<<<5384, 256, 0, stream>>>(x, W1, W2, eidx, wsi, xb, w1t, w2t, act, out);
    gemm2_kernel<<<dim3(16, 64, NEXP), 256, 0, stream>>>(act, w2t, wsi, p, out);
}

// Round 12
// 39872.202 us; speedup vs baseline: 9.1778x; 2.2157x over previous
//
#include <hip/hip_runtime.h>

// MoE GLU MLP: E=8, D=1024, H=1024, K=2, N=2048 tokens, 4096 pairs.
// R19 = R18 with the consumer poll fixed: relaxed agent-scope atomic LOAD was
// served forever by the consumer XCD's stale private L2 (cross-XCD trap, G16);
// producers' atomicAdd RMW lands at the coherent point (MALL) which plain loads
// never re-fetch. Fix: poll via atomicAdd(f, 0) (RMW -> executes at MALL,
// returns true value). R18's 88ms == 3 x full spin bound, exactly matching this
// mechanism. Data path already correct (threadfence release/acquire pair).
// Structure unchanged: ONE mega-kernel [bucket 8 | xcvt 256 | W1cvt 2048 |
// per-e: W2cvt 128 + gemm1 192 | outzero 512]; gemm2 separate (R16 exact).

typedef __bf16 bf16x8 __attribute__((ext_vector_type(8)));
typedef __bf16 bf16x4 __attribute__((ext_vector_type(4)));
typedef float  f32x4  __attribute__((ext_vector_type(4)));

#define NPAIR 4096
#define NTOK  2048
#define DDIM  1024
#define HDIM  1024
#define NEXP  8

// workspace layout (bytes)
#define ORDER_I   64                      // int index of order[]; max extent < 5176
#define FLAGS_I   6000                    // int index of flags (order ends <5176; xb at 6144)
#define FB        0                       // F[FB+e]  : bucket(e) done (target 1)
#define FX        8                       // F[FX]    : all xcvt done (target 256)
#define FW1       9                       // F[FW1+e] : W1cvt(e) done (target 256)
#define XB_OFF    (24576)                 // bf16 x        [2048][1024]   4 MB
#define W1T_OFF   (XB_OFF + 4194304)      // bf16 W1^T  [8][2048][1024]  32 MB
#define W2T_OFF   (W1T_OFF + 33554432)    // bf16 W2^T  [8][1024][1024]  16 MB
#define ACT_OFF   (W2T_OFF + 16777216)    // bf16 act      [5120][1024] 10.5 MB

#define GLOAD_LDS16(g, l) \
    __builtin_amdgcn_global_load_lds( \
        (const __attribute__((address_space(1))) void*)(g), \
        (__attribute__((address_space(3))) void*)(l), 16, 0, 0)

__device__ __forceinline__ void release_inc(int* f) {
    __threadfence();                      // agent release: L2 writeback of prior stores
    atomicAdd(f, 1);                      // RMW at coherent point
}
__device__ __forceinline__ void acquire_wait(int* f, int target) {
    for (int i = 0; i < 20000; ++i) {     // bounded (~9ms worst); healthy wait ~us
        if (atomicAdd(f, 0) >= target)    // RMW poll: reads TRUE value at MALL
            return;
        __builtin_amdgcn_s_sleep(8);
    }
}

// 64k x 128c transpose-convert: global_load_lds stage -> one barrier ->
// 8x ds_read_b128 per thread -> reg 8x4 transpose -> bf16x8 stores.
__device__ __forceinline__ void tcvt2(const float* __restrict__ s,
                                      __bf16* __restrict__ d,
                                      int R, int C, int k0, int c0,
                                      float* tt, int tid) {
#pragma unroll
    for (int j = 0; j < 8; j++) {
        int c = j * 256 + tid;
        int row = c >> 5, col = (c & 31) * 4;
        GLOAD_LDS16(s + (size_t)(k0 + row) * C + c0 + col, (char*)tt + c * 16);
    }
    __syncthreads();                       // drains vmcnt(0) + barrier
    const int a = tid >> 5, b = tid & 31;
    f32x4 v[8];
#pragma unroll
    for (int jj = 0; jj < 8; jj++)
        v[jj] = *(const f32x4*)(tt + (8 * a + jj) * 128 + 4 * b);
#pragma unroll
    for (int ii = 0; ii < 4; ii++) {
        bf16x8 o;
#pragma unroll
        for (int jj = 0; jj < 8; jj++) o[jj] = (__bf16)v[jj][ii];
        *(bf16x8*)(d + (size_t)(c0 + 4 * b + ii) * R + k0 + 8 * a) = o;
    }
}

// ---------------- mega: bucket | xcvt | W1cvt | per-e {W2cvt, gemm1} | outzero ----------------
__global__ __launch_bounds__(256) void mega_kernel(const float* __restrict__ x,
                                                   const float* __restrict__ W1,
                                                   const float* __restrict__ W2,
                                                   const int* __restrict__ idx,
                                                   int* __restrict__ wsi,
                                                   __bf16* __restrict__ xb,
                                                   __bf16* __restrict__ w1t,
                                                   __bf16* __restrict__ w2t,
                                                   __bf16* __restrict__ act,
                                                   float* __restrict__ out) {
    __shared__ __align__(16) char smem[49152];   // GEMM: 2x(As 8K|Bs 16K); cvt: 32K fp32
    const int b = blockIdx.x;
    const int tid = threadIdx.x;
    int* F = wsi + FLAGS_I;

    if (b < 8) {
        // ---- bucket(e = b) ----
        __shared__ int cnt[NEXP];
        __shared__ int sbase, scur;
        const int e = b;
        if (tid < NEXP) cnt[tid] = 0;
        if (tid == 0) scur = 0;
        __syncthreads();
        for (int i = tid; i < NPAIR; i += 256) atomicAdd(&cnt[idx[i] & 7], 1);
        __syncthreads();
        if (tid == 0) {
            int off = 0;
            for (int e2 = 0; e2 < NEXP; e2++) {
                if (e2 == e) { wsi[e] = cnt[e]; wsi[8 + e] = off; sbase = off; }
                off += (cnt[e2] + 127) & ~127;
            }
        }
        __syncthreads();
        for (int i = tid; i < NPAIR; i += 256) {
            if ((idx[i] & 7) == e) {
                int s = atomicAdd(&scur, 1);
                wsi[ORDER_I + sbase + s] = i;
            }
        }
        __syncthreads();
        if (tid == 0) release_inc(&F[FB + e]);
        return;
    }
    if (b < 264) {
        // ---- xcvt (256 blocks x 8192 elems) ----
        size_t base = (size_t)(b - 8) * 8192 + tid * 8;
#pragma unroll
        for (int j = 0; j < 4; j++) {
            const float* sp = x + base + j * 2048;
            f32x4 v0 = *(const f32x4*)sp;
            f32x4 v1 = *(const f32x4*)(sp + 4);
            bf16x8 o;
            o[0] = (__bf16)v0[0]; o[1] = (__bf16)v0[1]; o[2] = (__bf16)v0[2]; o[3] = (__bf16)v0[3];
            o[4] = (__bf16)v1[0]; o[5] = (__bf16)v1[1]; o[6] = (__bf16)v1[2]; o[7] = (__bf16)v1[3];
            *(bf16x8*)(xb + base + j * 2048) = o;
        }
        __syncthreads();
        if (tid == 0) release_inc(&F[FX]);
        return;
    }
    if (b < 2312) {
        // ---- W1cvt, e-major (256 tiles/e) ----
        int i = b - 264;
        int e = i >> 8, t2 = i & 255;
        int k0 = (t2 & 15) * 64, c0 = (t2 >> 4) * 128;
        tcvt2(W1 + (size_t)e * DDIM * 2 * HDIM, w1t + (size_t)e * 2 * HDIM * DDIM,
              DDIM, 2 * HDIM, k0, c0, (float*)smem, tid);
        __syncthreads();
        if (tid == 0) release_inc(&F[FW1 + e]);
        return;
    }
    if (b >= 4872) {
        // ---- outzero (512 blocks zero 8 MB of out) ----
        int zb = b - 4872;
        float4 z4 = {0.f, 0.f, 0.f, 0.f};
        int b4 = zb * 4096;
#pragma unroll
        for (int j = 0; j < 4; j++)
            *(float4*)(out + b4 + j * 1024 + tid * 4) = z4;
        return;
    }

    // ---- per-e group: W2cvt (r<128) then gemm1 (r>=128) ----
    int i = b - 2312;
    const int e = i / 320;
    int r = i % 320;
    if (r < 128) {
        int k0 = (r & 15) * 64, c0 = (r >> 4) * 128;
        tcvt2(W2 + (size_t)e * HDIM * DDIM, w2t + (size_t)e * DDIM * HDIM,
              HDIM, DDIM, k0, c0, (float*)smem, tid);
        return;
    }
    r -= 128;                                // 0..191: n0t = r/12, mt = r%12
    const int n0 = (r / 12) * 64;
    const int m0 = (r % 12) * 64;

    // ---- acquire deps: bucket(e), all xcvt, W1cvt(e) ----
    if (tid == 0) {
        acquire_wait(&F[FB + e], 1);
        acquire_wait(&F[FX], 256);
        acquire_wait(&F[FW1 + e], 256);
        __threadfence();                     // acquire: invalidate stale cache lines
    }
    __syncthreads();

    const int cnt = wsi[e];
    if (m0 >= cnt) return;
    const int base = wsi[8 + e];
    const int* order = wsi + ORDER_I;
    const __bf16* w1e = w1t + (size_t)e * 2048 * 1024;

    const int lane = tid & 63, w = tid >> 6;
    const int lm = lane & 15, q = lane >> 4;
    const int wm = w & 1, wn = w >> 1;
    const int x7 = lm & 7;
    const int sw0 = (q ^ x7) * 16;
    const int sw1 = ((4 + q) ^ x7) * 16;

    const __bf16* ga[2];
    const __bf16* gb[4];
#pragma unroll
    for (int j = 0; j < 2; j++) {
        int c = j * 256 + tid;
        int rr2 = c >> 3;
        int ks = ((c & 7) ^ (rr2 & 7)) * 8;
        int m = m0 + rr2; if (m >= cnt) m = cnt - 1;
        int tok = order[base + m] >> 1;
        ga[j] = xb + (size_t)tok * DDIM + ks;
    }
#pragma unroll
    for (int j = 0; j < 4; j++) {
        int c = j * 256 + tid;
        int rr2 = c >> 3;
        int ks = ((c & 7) ^ (rr2 & 7)) * 8;
        int half = rr2 >> 6, rr = rr2 & 63;
        int rb = (rr < 32) ? (n0 + half * 32 + rr)
                           : (HDIM + n0 + half * 32 + (rr - 32));
        gb[j] = w1e + (size_t)rb * DDIM + ks;
    }

    f32x4 acc[2][4];
#pragma unroll
    for (int mt = 0; mt < 2; mt++)
#pragma unroll
        for (int nt = 0; nt < 4; nt++) acc[mt][nt] = (f32x4){0.f, 0.f, 0.f, 0.f};

    // ---- prologue: issue tile 0 into buf0 (no drain) ----
#pragma unroll
    for (int j = 0; j < 2; j++) {
        GLOAD_LDS16(ga[j], smem + (j * 256 + tid) * 16);
        ga[j] += 64;
    }
#pragma unroll
    for (int j = 0; j < 4; j++) {
        GLOAD_LDS16(gb[j], smem + 8192 + (j * 256 + tid) * 16);
        gb[j] += 64;
    }

    // ---- 2-phase main loop, counted vmcnt ----
    for (int t = 0; t < 16; ++t) {
        char* cbase = smem + (t & 1) * 24576;
        if (t < 15) {
            char* nbase = smem + ((t + 1) & 1) * 24576;
#pragma unroll
            for (int j = 0; j < 2; j++) {
                GLOAD_LDS16(ga[j], nbase + (j * 256 + tid) * 16);
                ga[j] += 64;
            }
#pragma unroll
            for (int j = 0; j < 4; j++) {
                GLOAD_LDS16(gb[j], nbase + 8192 + (j * 256 + tid) * 16);
                gb[j] += 64;
            }
            asm volatile("s_waitcnt vmcnt(6)" ::: "memory");   // tile t landed
        } else {
            asm volatile("s_waitcnt vmcnt(0)" ::: "memory");
        }
        __builtin_amdgcn_s_barrier();
        __builtin_amdgcn_sched_barrier(0);
        __bf16 (*As)[64] = (__bf16 (*)[64])cbase;
        __bf16 (*Bs)[64] = (__bf16 (*)[64])(cbase + 8192);
#pragma unroll
        for (int kh = 0; kh < 2; kh++) {
            const int sw = kh ? sw1 : sw0;
            bf16x8 af[2];
#pragma unroll
            for (int mt = 0; mt < 2; mt++)
                af[mt] = *(const bf16x8*)((const char*)&As[wm * 32 + mt * 16 + lm][0] + sw);
            __builtin_amdgcn_s_setprio(1);
#pragma unroll
            for (int nt = 0; nt < 4; nt++) {
                bf16x8 bfr = *(const bf16x8*)((const char*)&Bs[wn * 64 + nt * 16 + lm][0] + sw);
#pragma unroll
                for (int mt = 0; mt < 2; mt++)
                    acc[mt][nt] = __builtin_amdgcn_mfma_f32_16x16x32_bf16(af[mt], bfr, acc[mt][nt], 0, 0, 0);
            }
            __builtin_amdgcn_s_setprio(0);
        }
        __builtin_amdgcn_sched_barrier(0);
        __builtin_amdgcn_s_barrier();
    }

#pragma unroll
    for (int mt = 0; mt < 2; mt++) {
        int mbase = m0 + wm * 32 + mt * 16 + q * 4;
#pragma unroll
        for (int ntp = 0; ntp < 2; ntp++) {
            int col = n0 + wn * 32 + ntp * 16 + lm;
#pragma unroll
            for (int rr = 0; rr < 4; rr++) {
                int m = mbase + rr;
                if (m < cnt) {
                    float h = acc[mt][ntp][rr];
                    float g = acc[mt][ntp + 2][rr];
                    float a = h * (g / (1.f + __expf(-g)));
                    act[(size_t)(base + m) * HDIM + col] = (__bf16)a;
                }
            }
        }
    }
}

// ---------------- gemm2: 64m x 64n, counted vmcnt, fused atomic combine (R16 exact) ----------------
__global__ __launch_bounds__(256) void gemm2_kernel(const __bf16* __restrict__ act,
                                                    const __bf16* __restrict__ w2t,
                                                    const int* __restrict__ wsi,
                                                    const float* __restrict__ p,
                                                    float* __restrict__ out) {
    const int e = blockIdx.z;
    const int cnt = wsi[e];
    const int m0 = blockIdx.y * 64;
    if (m0 >= cnt) return;
    const int base = wsi[8 + e];
    const int n0 = blockIdx.x * 64;
    const int* order = wsi + ORDER_I;
    const __bf16* w2e = w2t + (size_t)e * 1024 * 1024;

    __shared__ __align__(16) char smem[32768];   // 2 x (As 8K | Bs 8K)

    const int tid = threadIdx.x;
    const int lane = tid & 63, w = tid >> 6;
    const int lm = lane & 15, q = lane >> 4;
    const int wm = w & 1, wn = w >> 1;
    const int x7 = lm & 7;
    const int sw0 = (q ^ x7) * 16;
    const int sw1 = ((4 + q) ^ x7) * 16;

    const __bf16* ga[2];
    const __bf16* gb[2];
#pragma unroll
    for (int j = 0; j < 2; j++) {
        int c = j * 256 + tid;
        int r = c >> 3;
        int ks = ((c & 7) ^ (r & 7)) * 8;
        ga[j] = act + (size_t)(base + m0 + r) * HDIM + ks;   // pad rows masked at epilogue
        gb[j] = w2e + (size_t)(n0 + r) * HDIM + ks;
    }

    f32x4 acc[2][2];
#pragma unroll
    for (int mt = 0; mt < 2; mt++)
#pragma unroll
        for (int nt = 0; nt < 2; nt++) acc[mt][nt] = (f32x4){0.f, 0.f, 0.f, 0.f};

#pragma unroll
    for (int j = 0; j < 2; j++) {
        GLOAD_LDS16(ga[j], smem + (j * 256 + tid) * 16);
        GLOAD_LDS16(gb[j], smem + 8192 + (j * 256 + tid) * 16);
        ga[j] += 64; gb[j] += 64;
    }

    for (int t = 0; t < 16; ++t) {
        char* cbase = smem + (t & 1) * 16384;
        if (t < 15) {
            char* nbase = smem + ((t + 1) & 1) * 16384;
#pragma unroll
            for (int j = 0; j < 2; j++) {
                GLOAD_LDS16(ga[j], nbase + (j * 256 + tid) * 16);
                GLOAD_LDS16(gb[j], nbase + 8192 + (j * 256 + tid) * 16);
                ga[j] += 64; gb[j] += 64;
            }
            asm volatile("s_waitcnt vmcnt(4)" ::: "memory");   // tile t landed
        } else {
            asm volatile("s_waitcnt vmcnt(0)" ::: "memory");
        }
        __builtin_amdgcn_s_barrier();
        __builtin_amdgcn_sched_barrier(0);
        __bf16 (*As)[64] = (__bf16 (*)[64])cbase;
        __bf16 (*Bs)[64] = (__bf16 (*)[64])(cbase + 8192);
#pragma unroll
        for (int kh = 0; kh < 2; kh++) {
            const int sw = kh ? sw1 : sw0;
            bf16x8 af[2];
#pragma unroll
            for (int mt = 0; mt < 2; mt++)
                af[mt] = *(const bf16x8*)((const char*)&As[wm * 32 + mt * 16 + lm][0] + sw);
            __builtin_amdgcn_s_setprio(1);
#pragma unroll
            for (int nt = 0; nt < 2; nt++) {
                bf16x8 bfr = *(const bf16x8*)((const char*)&Bs[wn * 32 + nt * 16 + lm][0] + sw);
#pragma unroll
                for (int mt = 0; mt < 2; mt++)
                    acc[mt][nt] = __builtin_amdgcn_mfma_f32_16x16x32_bf16(af[mt], bfr, acc[mt][nt], 0, 0, 0);
            }
            __builtin_amdgcn_s_setprio(0);
        }
        __builtin_amdgcn_sched_barrier(0);
        __builtin_amdgcn_s_barrier();
    }

    int pi[2][4];
    float pw[2][4];
#pragma unroll
    for (int mt = 0; mt < 2; mt++)
#pragma unroll
        for (int r = 0; r < 4; r++) {
            int gm = m0 + wm * 32 + mt * 16 + q * 4 + r;
            if (gm < cnt) {
                int pr = order[base + gm];
                pi[mt][r] = pr;
                pw[mt][r] = p[pr];
            } else pi[mt][r] = -1;
        }
#pragma unroll
    for (int mt = 0; mt < 2; mt++)
#pragma unroll
        for (int nt = 0; nt < 2; nt++) {
            int col = n0 + wn * 32 + nt * 16 + lm;
#pragma unroll
            for (int r = 0; r < 4; r++) {
                if (pi[mt][r] >= 0) {
                    int tok = pi[mt][r] >> 1;
                    atomicAdd(out + (size_t)tok * DDIM + col, pw[mt][r] * acc[mt][nt][r]);
                }
            }
        }
}

extern "C" void kernel_launch(void* const* d_in, const int* in_sizes, int n_in,
                              void* d_out, int out_size, void* d_ws, size_t ws_size,
                              hipStream_t stream) {
    (void)in_sizes; (void)n_in; (void)out_size; (void)ws_size;
    const float* x   = (const float*)d_in[0];
    const float* p   = (const float*)d_in[1];
    const int* eidx  = (const int*)d_in[2];
    const float* W1  = (const float*)d_in[3];
    const float* W2  = (const float*)d_in[4];
    float* out = (float*)d_out;

    char* ws = (char*)d_ws;
    int* wsi     = (int*)ws;
    __bf16* xb   = (__bf16*)(ws + XB_OFF);
    __bf16* w1t  = (__bf16*)(ws + W1T_OFF);
    __bf16* w2t  = (__bf16*)(ws + W2T_OFF);
    __bf16* act  = (__bf16*)(ws + ACT_OFF);

    // 8 bucket + 256 xcvt + 2048 W1cvt + 8*(128 W2cvt + 192 gemm1) + 512 outzero = 5384
    mega_kernel<<<5384, 256, 0, stream>>>(x, W1, W2, eidx, wsi, xb, w1t, w2t, act, out);
    gemm2_kernel<<<dim3(16, 64, NEXP), 256, 0, stream>>>(act, w2t, wsi, p, out);
}

// Round 13
// 581.147 us; speedup vs baseline: 629.6840x; 68.6095x over previous
//
#include <hip/hip_runtime.h>

// MoE GLU MLP: E=8, D=1024, H=1024, K=2, N=2048 tokens, 4096 pairs.
// R20 = R19 with POISON-PROOF flags. R17/18/19 all spun to full bound because the
// harness RE-POISONS the workspace each iteration (the 256MiB fill): counter flags
// start at poison (e.g. 0xCDCDCDCD), so poison+N never reaches the target. Fix:
// write-once MAGIC flags (atomicExch) - one per producer BLOCK - and thread-parallel
// equality polling (tid t checks xcvt flag[t] & W1cvt flag[e*256+t]; tid0 checks
// bucket[e]) reduced via __syncthreads_and. Correct for any poison != MAGIC and
// for zeroed ws. Flags in a dedicated region outside order[]'s span; data offsets
// shift +8KB. GEMM bodies / gemm2 / block structure unchanged (R19).

typedef __bf16 bf16x8 __attribute__((ext_vector_type(8)));
typedef __bf16 bf16x4 __attribute__((ext_vector_type(4)));
typedef float  f32x4  __attribute__((ext_vector_type(4)));

#define NPAIR 4096
#define NTOK  2048
#define DDIM  1024
#define HDIM  1024
#define NEXP  8
#define MAGIC 0x5EED9A7E

// workspace layout
#define ORDER_I   64                      // int index of order[]; span < [64,5176)
#define FLAGS_I   5248                    // int index of flags: 8 FB | 256 FX | 2048 FW1
                                          // ends at int 7560 (byte 30240)
#define XB_OFF    (32768)                 // bf16 x        [2048][1024]   4 MB
#define W1T_OFF   (XB_OFF + 4194304)      // bf16 W1^T  [8][2048][1024]  32 MB
#define W2T_OFF   (W1T_OFF + 33554432)    // bf16 W2^T  [8][1024][1024]  16 MB
#define ACT_OFF   (W2T_OFF + 16777216)    // bf16 act      [5120][1024] 10.5 MB

#define GLOAD_LDS16(g, l) \
    __builtin_amdgcn_global_load_lds( \
        (const __attribute__((address_space(1))) void*)(g), \
        (__attribute__((address_space(3))) void*)(l), 16, 0, 0)

// producer release: all block stores visible (syncthreads), then L2 writeback,
// then write-once MAGIC at the coherent point.
__device__ __forceinline__ void release_flag(int* f) {
    __threadfence();
    atomicExch(f, MAGIC);
}

// 64k x 128c transpose-convert: global_load_lds stage -> one barrier ->
// 8x ds_read_b128 per thread -> reg 8x4 transpose -> bf16x8 stores.
__device__ __forceinline__ void tcvt2(const float* __restrict__ s,
                                      __bf16* __restrict__ d,
                                      int R, int C, int k0, int c0,
                                      float* tt, int tid) {
#pragma unroll
    for (int j = 0; j < 8; j++) {
        int c = j * 256 + tid;
        int row = c >> 5, col = (c & 31) * 4;
        GLOAD_LDS16(s + (size_t)(k0 + row) * C + c0 + col, (char*)tt + c * 16);
    }
    __syncthreads();                       // drains vmcnt(0) + barrier
    const int a = tid >> 5, b = tid & 31;
    f32x4 v[8];
#pragma unroll
    for (int jj = 0; jj < 8; jj++)
        v[jj] = *(const f32x4*)(tt + (8 * a + jj) * 128 + 4 * b);
#pragma unroll
    for (int ii = 0; ii < 4; ii++) {
        bf16x8 o;
#pragma unroll
        for (int jj = 0; jj < 8; jj++) o[jj] = (__bf16)v[jj][ii];
        *(bf16x8*)(d + (size_t)(c0 + 4 * b + ii) * R + k0 + 8 * a) = o;
    }
}

// ---------------- mega: bucket | xcvt | W1cvt | per-e {W2cvt, gemm1} | outzero ----------------
__global__ __launch_bounds__(256) void mega_kernel(const float* __restrict__ x,
                                                   const float* __restrict__ W1,
                                                   const float* __restrict__ W2,
                                                   const int* __restrict__ idx,
                                                   int* __restrict__ wsi,
                                                   __bf16* __restrict__ xb,
                                                   __bf16* __restrict__ w1t,
                                                   __bf16* __restrict__ w2t,
                                                   __bf16* __restrict__ act,
                                                   float* __restrict__ out) {
    __shared__ __align__(16) char smem[49152];   // GEMM: 2x(As 8K|Bs 16K); cvt: 32K fp32
    const int b = blockIdx.x;
    const int tid = threadIdx.x;
    int* F = wsi + FLAGS_I;                      // [0,8): FB  [8,264): FX  [264,2312): FW1

    if (b < 8) {
        // ---- bucket(e = b) ----
        __shared__ int cnt[NEXP];
        __shared__ int sbase, scur;
        const int e = b;
        if (tid < NEXP) cnt[tid] = 0;
        if (tid == 0) scur = 0;
        __syncthreads();
        for (int i = tid; i < NPAIR; i += 256) atomicAdd(&cnt[idx[i] & 7], 1);
        __syncthreads();
        if (tid == 0) {
            int off = 0;
            for (int e2 = 0; e2 < NEXP; e2++) {
                if (e2 == e) { wsi[e] = cnt[e]; wsi[8 + e] = off; sbase = off; }
                off += (cnt[e2] + 127) & ~127;
            }
        }
        __syncthreads();
        for (int i = tid; i < NPAIR; i += 256) {
            if ((idx[i] & 7) == e) {
                int s = atomicAdd(&scur, 1);
                wsi[ORDER_I + sbase + s] = i;
            }
        }
        __syncthreads();
        if (tid == 0) release_flag(&F[e]);
        return;
    }
    if (b < 264) {
        // ---- xcvt (256 blocks x 8192 elems) ----
        size_t base = (size_t)(b - 8) * 8192 + tid * 8;
#pragma unroll
        for (int j = 0; j < 4; j++) {
            const float* sp = x + base + j * 2048;
            f32x4 v0 = *(const f32x4*)sp;
            f32x4 v1 = *(const f32x4*)(sp + 4);
            bf16x8 o;
            o[0] = (__bf16)v0[0]; o[1] = (__bf16)v0[1]; o[2] = (__bf16)v0[2]; o[3] = (__bf16)v0[3];
            o[4] = (__bf16)v1[0]; o[5] = (__bf16)v1[1]; o[6] = (__bf16)v1[2]; o[7] = (__bf16)v1[3];
            *(bf16x8*)(xb + base + j * 2048) = o;
        }
        __syncthreads();
        if (tid == 0) release_flag(&F[8 + (b - 8)]);
        return;
    }
    if (b < 2312) {
        // ---- W1cvt, e-major (256 tiles/e) ----
        int i = b - 264;
        int e = i >> 8, t2 = i & 255;
        int k0 = (t2 & 15) * 64, c0 = (t2 >> 4) * 128;
        tcvt2(W1 + (size_t)e * DDIM * 2 * HDIM, w1t + (size_t)e * 2 * HDIM * DDIM,
              DDIM, 2 * HDIM, k0, c0, (float*)smem, tid);
        __syncthreads();
        if (tid == 0) release_flag(&F[264 + i]);
        return;
    }
    if (b >= 4872) {
        // ---- outzero (512 blocks zero 8 MB of out) ----
        int zb = b - 4872;
        float4 z4 = {0.f, 0.f, 0.f, 0.f};
        int b4 = zb * 4096;
#pragma unroll
        for (int j = 0; j < 4; j++)
            *(float4*)(out + b4 + j * 1024 + tid * 4) = z4;
        return;
    }

    // ---- per-e group: W2cvt (r<128) then gemm1 (r>=128) ----
    int i = b - 2312;
    const int e = i / 320;
    int r = i % 320;
    if (r < 128) {
        int k0 = (r & 15) * 64, c0 = (r >> 4) * 128;
        tcvt2(W2 + (size_t)e * HDIM * DDIM, w2t + (size_t)e * DDIM * HDIM,
              HDIM, DDIM, k0, c0, (float*)smem, tid);
        return;
    }
    r -= 128;                                // 0..191: n0t = r/12, mt = r%12
    const int n0 = (r / 12) * 64;
    const int m0 = (r % 12) * 64;

    // ---- acquire deps (thread-parallel, poison-proof equality poll) ----
    {
        bool done = false;
        for (int it = 0; it < 4000 && !done; ++it) {
            int okx = (atomicAdd(&F[8 + tid], 0) == MAGIC);
            int okw = (atomicAdd(&F[264 + e * 256 + tid], 0) == MAGIC);
            int okb = (tid == 0) ? (atomicAdd(&F[e], 0) == MAGIC) : 1;
            done = __syncthreads_and(okx && okw && okb) != 0;
            if (!done) __builtin_amdgcn_s_sleep(8);
        }
        __threadfence();                     // acquire: invalidate stale cache lines
        __syncthreads();
    }

    const int cnt = wsi[e];
    if (m0 >= cnt) return;
    const int base = wsi[8 + e];
    const int* order = wsi + ORDER_I;
    const __bf16* w1e = w1t + (size_t)e * 2048 * 1024;

    const int lane = tid & 63, w = tid >> 6;
    const int lm = lane & 15, q = lane >> 4;
    const int wm = w & 1, wn = w >> 1;
    const int x7 = lm & 7;
    const int sw0 = (q ^ x7) * 16;
    const int sw1 = ((4 + q) ^ x7) * 16;

    const __bf16* ga[2];
    const __bf16* gb[4];
#pragma unroll
    for (int j = 0; j < 2; j++) {
        int c = j * 256 + tid;
        int rr2 = c >> 3;
        int ks = ((c & 7) ^ (rr2 & 7)) * 8;
        int m = m0 + rr2; if (m >= cnt) m = cnt - 1;
        int tok = order[base + m] >> 1;
        ga[j] = xb + (size_t)tok * DDIM + ks;
    }
#pragma unroll
    for (int j = 0; j < 4; j++) {
        int c = j * 256 + tid;
        int rr2 = c >> 3;
        int ks = ((c & 7) ^ (rr2 & 7)) * 8;
        int half = rr2 >> 6, rr = rr2 & 63;
        int rb = (rr < 32) ? (n0 + half * 32 + rr)
                           : (HDIM + n0 + half * 32 + (rr - 32));
        gb[j] = w1e + (size_t)rb * DDIM + ks;
    }

    f32x4 acc[2][4];
#pragma unroll
    for (int mt = 0; mt < 2; mt++)
#pragma unroll
        for (int nt = 0; nt < 4; nt++) acc[mt][nt] = (f32x4){0.f, 0.f, 0.f, 0.f};

    // ---- prologue: issue tile 0 into buf0 (no drain) ----
#pragma unroll
    for (int j = 0; j < 2; j++) {
        GLOAD_LDS16(ga[j], smem + (j * 256 + tid) * 16);
        ga[j] += 64;
    }
#pragma unroll
    for (int j = 0; j < 4; j++) {
        GLOAD_LDS16(gb[j], smem + 8192 + (j * 256 + tid) * 16);
        gb[j] += 64;
    }

    // ---- 2-phase main loop, counted vmcnt ----
    for (int t = 0; t < 16; ++t) {
        char* cbase = smem + (t & 1) * 24576;
        if (t < 15) {
            char* nbase = smem + ((t + 1) & 1) * 24576;
#pragma unroll
            for (int j = 0; j < 2; j++) {
                GLOAD_LDS16(ga[j], nbase + (j * 256 + tid) * 16);
                ga[j] += 64;
            }
#pragma unroll
            for (int j = 0; j < 4; j++) {
                GLOAD_LDS16(gb[j], nbase + 8192 + (j * 256 + tid) * 16);
                gb[j] += 64;
            }
            asm volatile("s_waitcnt vmcnt(6)" ::: "memory");   // tile t landed
        } else {
            asm volatile("s_waitcnt vmcnt(0)" ::: "memory");
        }
        __builtin_amdgcn_s_barrier();
        __builtin_amdgcn_sched_barrier(0);
        __bf16 (*As)[64] = (__bf16 (*)[64])cbase;
        __bf16 (*Bs)[64] = (__bf16 (*)[64])(cbase + 8192);
#pragma unroll
        for (int kh = 0; kh < 2; kh++) {
            const int sw = kh ? sw1 : sw0;
            bf16x8 af[2];
#pragma unroll
            for (int mt = 0; mt < 2; mt++)
                af[mt] = *(const bf16x8*)((const char*)&As[wm * 32 + mt * 16 + lm][0] + sw);
            __builtin_amdgcn_s_setprio(1);
#pragma unroll
            for (int nt = 0; nt < 4; nt++) {
                bf16x8 bfr = *(const bf16x8*)((const char*)&Bs[wn * 64 + nt * 16 + lm][0] + sw);
#pragma unroll
                for (int mt = 0; mt < 2; mt++)
                    acc[mt][nt] = __builtin_amdgcn_mfma_f32_16x16x32_bf16(af[mt], bfr, acc[mt][nt], 0, 0, 0);
            }
            __builtin_amdgcn_s_setprio(0);
        }
        __builtin_amdgcn_sched_barrier(0);
        __builtin_amdgcn_s_barrier();
    }

#pragma unroll
    for (int mt = 0; mt < 2; mt++) {
        int mbase = m0 + wm * 32 + mt * 16 + q * 4;
#pragma unroll
        for (int ntp = 0; ntp < 2; ntp++) {
            int col = n0 + wn * 32 + ntp * 16 + lm;
#pragma unroll
            for (int rr = 0; rr < 4; rr++) {
                int m = mbase + rr;
                if (m < cnt) {
                    float h = acc[mt][ntp][rr];
                    float g = acc[mt][ntp + 2][rr];
                    float a = h * (g / (1.f + __expf(-g)));
                    act[(size_t)(base + m) * HDIM + col] = (__bf16)a;
                }
            }
        }
    }
}

// ---------------- gemm2: 64m x 64n, counted vmcnt, fused atomic combine (R16 exact) ----------------
__global__ __launch_bounds__(256) void gemm2_kernel(const __bf16* __restrict__ act,
                                                    const __bf16* __restrict__ w2t,
                                                    const int* __restrict__ wsi,
                                                    const float* __restrict__ p,
                                                    float* __restrict__ out) {
    const int e = blockIdx.z;
    const int cnt = wsi[e];
    const int m0 = blockIdx.y * 64;
    if (m0 >= cnt) return;
    const int base = wsi[8 + e];
    const int n0 = blockIdx.x * 64;
    const int* order = wsi + ORDER_I;
    const __bf16* w2e = w2t + (size_t)e * 1024 * 1024;

    __shared__ __align__(16) char smem[32768];   // 2 x (As 8K | Bs 8K)

    const int tid = threadIdx.x;
    const int lane = tid & 63, w = tid >> 6;
    const int lm = lane & 15, q = lane >> 4;
    const int wm = w & 1, wn = w >> 1;
    const int x7 = lm & 7;
    const int sw0 = (q ^ x7) * 16;
    const int sw1 = ((4 + q) ^ x7) * 16;

    const __bf16* ga[2];
    const __bf16* gb[2];
#pragma unroll
    for (int j = 0; j < 2; j++) {
        int c = j * 256 + tid;
        int r = c >> 3;
        int ks = ((c & 7) ^ (r & 7)) * 8;
        ga[j] = act + (size_t)(base + m0 + r) * HDIM + ks;   // pad rows masked at epilogue
        gb[j] = w2e + (size_t)(n0 + r) * HDIM + ks;
    }

    f32x4 acc[2][2];
#pragma unroll
    for (int mt = 0; mt < 2; mt++)
#pragma unroll
        for (int nt = 0; nt < 2; nt++) acc[mt][nt] = (f32x4){0.f, 0.f, 0.f, 0.f};

#pragma unroll
    for (int j = 0; j < 2; j++) {
        GLOAD_LDS16(ga[j], smem + (j * 256 + tid) * 16);
        GLOAD_LDS16(gb[j], smem + 8192 + (j * 256 + tid) * 16);
        ga[j] += 64; gb[j] += 64;
    }

    for (int t = 0; t < 16; ++t) {
        char* cbase = smem + (t & 1) * 16384;
        if (t < 15) {
            char* nbase = smem + ((t + 1) & 1) * 16384;
#pragma unroll
            for (int j = 0; j < 2; j++) {
                GLOAD_LDS16(ga[j], nbase + (j * 256 + tid) * 16);
                GLOAD_LDS16(gb[j], nbase + 8192 + (j * 256 + tid) * 16);
                ga[j] += 64; gb[j] += 64;
            }
            asm volatile("s_waitcnt vmcnt(4)" ::: "memory");   // tile t landed
        } else {
            asm volatile("s_waitcnt vmcnt(0)" ::: "memory");
        }
        __builtin_amdgcn_s_barrier();
        __builtin_amdgcn_sched_barrier(0);
        __bf16 (*As)[64] = (__bf16 (*)[64])cbase;
        __bf16 (*Bs)[64] = (__bf16 (*)[64])(cbase + 8192);
#pragma unroll
        for (int kh = 0; kh < 2; kh++) {
            const int sw = kh ? sw1 : sw0;
            bf16x8 af[2];
#pragma unroll
            for (int mt = 0; mt < 2; mt++)
                af[mt] = *(const bf16x8*)((const char*)&As[wm * 32 + mt * 16 + lm][0] + sw);
            __builtin_amdgcn_s_setprio(1);
#pragma unroll
            for (int nt = 0; nt < 2; nt++) {
                bf16x8 bfr = *(const bf16x8*)((const char*)&Bs[wn * 32 + nt * 16 + lm][0] + sw);
#pragma unroll
                for (int mt = 0; mt < 2; mt++)
                    acc[mt][nt] = __builtin_amdgcn_mfma_f32_16x16x32_bf16(af[mt], bfr, acc[mt][nt], 0, 0, 0);
            }
            __builtin_amdgcn_s_setprio(0);
        }
        __builtin_amdgcn_sched_barrier(0);
        __builtin_amdgcn_s_barrier();
    }

    int pi[2][4];
    float pw[2][4];
#pragma unroll
    for (int mt = 0; mt < 2; mt++)
#pragma unroll
        for (int r = 0; r < 4; r++) {
            int gm = m0 + wm * 32 + mt * 16 + q * 4 + r;
            if (gm < cnt) {
                int pr = order[base + gm];
                pi[mt][r] = pr;
                pw[mt][r] = p[pr];
            } else pi[mt][r] = -1;
        }
#pragma unroll
    for (int mt = 0; mt < 2; mt++)
#pragma unroll
        for (int nt = 0; nt < 2; nt++) {
            int col = n0 + wn * 32 + nt * 16 + lm;
#pragma unroll
            for (int r = 0; r < 4; r++) {
                if (pi[mt][r] >= 0) {
                    int tok = pi[mt][r] >> 1;
                    atomicAdd(out + (size_t)tok * DDIM + col, pw[mt][r] * acc[mt][nt][r]);
                }
            }
        }
}

extern "C" void kernel_launch(void* const* d_in, const int* in_sizes, int n_in,
                              void* d_out, int out_size, void* d_ws, size_t ws_size,
                              hipStream_t stream) {
    (void)in_sizes; (void)n_in; (void)out_size; (void)ws_size;
    const float* x   = (const float*)d_in[0];
    const float* p   = (const float*)d_in[1];
    const int* eidx  = (const int*)d_in[2];
    const float* W1  = (const float*)d_in[3];
    const float* W2  = (const float*)d_in[4];
    float* out = (float*)d_out;

    char* ws = (char*)d_ws;
    int* wsi     = (int*)ws;
    __bf16* xb   = (__bf16*)(ws + XB_OFF);
    __bf16* w1t  = (__bf16*)(ws + W1T_OFF);
    __bf16* w2t  = (__bf16*)(ws + W2T_OFF);
    __bf16* act  = (__bf16*)(ws + ACT_OFF);

    // 8 bucket + 256 xcvt + 2048 W1cvt + 8*(128 W2cvt + 192 gemm1) + 512 outzero = 5384
    mega_kernel<<<5384, 256, 0, stream>>>(x, W1, W2, eidx, wsi, xb, w1t, w2t, act, out);
    gemm2_kernel<<<dim3(16, 64, NEXP), 256, 0, stream>>>(act, w2t, wsi, p, out);
}